// Round 1
// 1283.712 us; speedup vs baseline: 1.2075x; 1.2075x over previous
//
#include <hip/hip_runtime.h>
#include <math.h>

#define N_NODES 50000
#define N_EDGES 500000
#define IN_DIM  128
#define NH      8
#define HD      16
#define OUTD    128   // NH*HD
#define CLAMP_V 5.0f

typedef unsigned short ushort_t;
typedef short bf16x8 __attribute__((ext_vector_type(8)));
typedef float f32x16 __attribute__((ext_vector_type(16)));

__device__ __forceinline__ ushort_t f2bf(float f) {
    uint32_t u = __float_as_uint(f);
    u += 0x7fffu + ((u >> 16) & 1u);          // round-to-nearest-even
    return (ushort_t)(u >> 16);
}
__device__ __forceinline__ float bf2f(ushort_t h) {
    return __uint_as_float(((uint32_t)h) << 16);
}

// ---------------------------------------------------------------------------
// Kernel 0: pack WE [128][256] f32 into transposed bf16 hi/lo [256 cols][128 k]
// ---------------------------------------------------------------------------
__global__ __launch_bounds__(256) void pack_we_kernel(
    const float* __restrict__ WE,
    ushort_t* __restrict__ hi, ushort_t* __restrict__ lo)
{
    int idx = blockIdx.x * 256 + threadIdx.x;   // 0..32767
    int n = idx & 255, k = idx >> 8;
    float v = WE[(size_t)k * 256 + n];
    ushort_t h = f2bf(v);
    hi[(size_t)n * 128 + k] = h;
    lo[(size_t)n * 128 + k] = f2bf(v - bf2f(h));
}

// ---------------------------------------------------------------------------
// Kernel 1: node GEMM (unchanged).  C-tile 64 nodes x 64 cols.  grid.y in [0,6)
// ---------------------------------------------------------------------------
__global__ __launch_bounds__(256) void node_gemm_kernel(
    const float* __restrict__ x,
    const float* __restrict__ WQ, const float* __restrict__ bQ,
    const float* __restrict__ WK, const float* __restrict__ bK,
    const float* __restrict__ WV, const float* __restrict__ bV,
    float* __restrict__ Vo, float* __restrict__ Kh, float* __restrict__ Vh)
{
    __shared__ float A[64][132];
    __shared__ float B[64][64];

    const int t  = threadIdx.x;
    const int bx = blockIdx.x;
    const int by = blockIdx.y;
    const int which = by >> 1;
    const int ch    = (by & 1) * 64;

    const float* W    = (which == 0) ? WQ : (which == 1 ? WK : WV);
    const float* bias = (which == 0) ? bQ : (which == 1 ? bK : bV);
    float*       out  = (which == 0) ? Vo : (which == 1 ? Kh : Vh);

    const int r0 = bx * 64;

    #pragma unroll
    for (int it = 0; it < 8; ++it) {
        int idx = it * 256 + t;
        int k4  = idx & 31;
        int r   = idx >> 5;
        float4 v = make_float4(0.f, 0.f, 0.f, 0.f);
        if (r0 + r < N_NODES)
            v = *(const float4*)(x + (size_t)(r0 + r) * IN_DIM + k4 * 4);
        *(float4*)&A[r][k4 * 4] = v;
    }

    const int tx = t & 15, ty = t >> 4;
    float acc[4][4] = {};

    for (int kh = 0; kh < 2; ++kh) {
        __syncthreads();
        #pragma unroll
        for (int it = 0; it < 4; ++it) {
            int idx = it * 256 + t;
            int c4  = idx & 15;
            int kk  = idx >> 4;
            float4 v = *(const float4*)(W + (size_t)(kh * 64 + kk) * 128 + ch + c4 * 4);
            *(float4*)&B[kk][c4 * 4] = v;
        }
        __syncthreads();

        #pragma unroll 4
        for (int k = 0; k < 64; k += 4) {
            float4 a4[4], b4[4];
            a4[0] = *(const float4*)&A[ty * 4 + 0][kh * 64 + k];
            a4[1] = *(const float4*)&A[ty * 4 + 1][kh * 64 + k];
            a4[2] = *(const float4*)&A[ty * 4 + 2][kh * 64 + k];
            a4[3] = *(const float4*)&A[ty * 4 + 3][kh * 64 + k];
            b4[0] = *(const float4*)&B[k + 0][tx * 4];
            b4[1] = *(const float4*)&B[k + 1][tx * 4];
            b4[2] = *(const float4*)&B[k + 2][tx * 4];
            b4[3] = *(const float4*)&B[k + 3][tx * 4];
            const float* aa = (const float*)a4;
            const float* bb = (const float*)b4;
            #pragma unroll
            for (int kk = 0; kk < 4; ++kk)
                #pragma unroll
                for (int i = 0; i < 4; ++i)
                    #pragma unroll
                    for (int j = 0; j < 4; ++j)
                        acc[i][j] += aa[i * 4 + kk] * bb[kk * 4 + j];
        }
    }

    #pragma unroll
    for (int i = 0; i < 4; ++i) {
        int r = r0 + ty * 4 + i;
        if (r < N_NODES) {
            #pragma unroll
            for (int j = 0; j < 4; ++j) {
                int c = ch + tx * 4 + j;
                out[(size_t)r * OUTD + c] = acc[i][j] + bias[c];
            }
        }
    }
}

// ---------------------------------------------------------------------------
// Kernel 2: edge GEMM via split-bf16 MFMA + fused epilogue.
// Tile: 128 edges x 128 cols (4 heads).  4 waves in 2x2, each 64x64 via
// 2x2 fragments of v_mfma_f32_32x32x16_bf16, K phased in halves of 64.
// hi/lo split: E*W ~= Ehi*Whi + Ehi*Wlo + Elo*Whi  (fp32-grade accuracy).
// LDS (64 KB): Eh[128][64] El Wh[128][64] Wl (bf16, XOR-swizzled), then
// reused as the f32 Ex stash [128][128] for the epilogue.
// ---------------------------------------------------------------------------
__global__ __launch_bounds__(256) void edge_kernel(
    const float* __restrict__ edge_attr,
    const int*   __restrict__ edge_index,
    const ushort_t* __restrict__ WEt_hi,
    const ushort_t* __restrict__ WEt_lo,
    const float* __restrict__ bE,
    const float* __restrict__ Aw,
    const float* __restrict__ Qh,     // = Vo region of d_out
    const float* __restrict__ Kh,
    float* __restrict__ conn_out,
    float* __restrict__ exp_s,
    float* __restrict__ denom)
{
    __shared__ ushort_t u16[32768];   // 64 KB: Eh@0, El@8192, Wh@16384, Wl@24576

    const int t   = threadIdx.x;
    const int bid = blockIdx.x;
    const int et  = bid >> 1;         // edge-tile; twin col-blocks adjacent -> L3 reuse
    const int ch  = bid & 1;
    const int e0  = et * 128;
    const int c0  = ch * 128;

    const int lane = t & 63;
    const int w    = t >> 6;
    const int we   = w >> 1;          // edge-half of tile
    const int wc   = w & 1;           // col-half of tile

    f32x16 acc[2][2];
    #pragma unroll
    for (int i = 0; i < 2; ++i)
        #pragma unroll
        for (int j = 0; j < 2; ++j)
            #pragma unroll
            for (int rgi = 0; rgi < 16; ++rgi)
                acc[i][j][rgi] = 0.f;

    #pragma unroll
    for (int kh = 0; kh < 2; ++kh) {
        __syncthreads();
        // ---- stage E: 128 rows x 64 k, f32 -> bf16 hi/lo, swizzled
        #pragma unroll
        for (int it = 0; it < 8; ++it) {
            int idx = it * 256 + t;        // 0..2047
            int k4  = idx & 15;
            int r   = idx >> 4;            // 0..127
            float4 v = make_float4(0.f, 0.f, 0.f, 0.f);
            if (e0 + r < N_EDGES)
                v = *(const float4*)(edge_attr + (size_t)(e0 + r) * IN_DIM + kh * 64 + k4 * 4);
            ushort_t ha = f2bf(v.x), hb = f2bf(v.y), hc = f2bf(v.z), hd = f2bf(v.w);
            ushort_t la = f2bf(v.x - bf2f(ha)), lb = f2bf(v.y - bf2f(hb)),
                     lc = f2bf(v.z - bf2f(hc)), ld = f2bf(v.w - bf2f(hd));
            int off = r * 64 + ((k4 * 4) ^ ((r & 7) << 3));
            *(uint2*)&u16[off]        = make_uint2((uint32_t)ha | ((uint32_t)hb << 16),
                                                   (uint32_t)hc | ((uint32_t)hd << 16));
            *(uint2*)&u16[8192 + off] = make_uint2((uint32_t)la | ((uint32_t)lb << 16),
                                                   (uint32_t)lc | ((uint32_t)ld << 16));
        }
        // ---- stage W: 128 cols x 64 k from packed bf16 global, swizzled
        #pragma unroll
        for (int it = 0; it < 4; ++it) {
            int idx = it * 256 + t;        // 0..1023
            int kc  = idx & 7;
            int c   = idx >> 3;            // 0..127
            size_t goff = (size_t)(c0 + c) * 128 + kh * 64 + kc * 8;
            int off = c * 64 + ((kc * 8) ^ ((c & 7) << 3));
            *(uint4*)&u16[16384 + off] = *(const uint4*)&WEt_hi[goff];
            *(uint4*)&u16[24576 + off] = *(const uint4*)&WEt_lo[goff];
        }
        __syncthreads();

        // ---- MFMA over this k-half: 4 ksteps of 16
        #pragma unroll
        for (int ks = 0; ks < 4; ++ks) {
            const int kloc = ks * 16 + ((lane >> 5) << 3);
            bf16x8 eh[2], el[2], wh2[2], wl2[2];
            #pragma unroll
            for (int f = 0; f < 2; ++f) {
                int er = we * 64 + f * 32 + (lane & 31);
                int eo = er * 64 + (kloc ^ ((er & 7) << 3));
                eh[f] = *(bf16x8*)&u16[eo];
                el[f] = *(bf16x8*)&u16[8192 + eo];
                int cr = wc * 64 + f * 32 + (lane & 31);
                int co = cr * 64 + (kloc ^ ((cr & 7) << 3));
                wh2[f] = *(bf16x8*)&u16[16384 + co];
                wl2[f] = *(bf16x8*)&u16[24576 + co];
            }
            #pragma unroll
            for (int i = 0; i < 2; ++i)
                #pragma unroll
                for (int j = 0; j < 2; ++j) {
                    acc[i][j] = __builtin_amdgcn_mfma_f32_32x32x16_bf16(eh[i], wh2[j], acc[i][j], 0, 0, 0);
                    acc[i][j] = __builtin_amdgcn_mfma_f32_32x32x16_bf16(eh[i], wl2[j], acc[i][j], 0, 0, 0);
                    acc[i][j] = __builtin_amdgcn_mfma_f32_32x32x16_bf16(el[i], wh2[j], acc[i][j], 0, 0, 0);
                }
        }
    }
    __syncthreads();

    // ---- stash Ex (+bias) into LDS as f32 [128][128]
    float* stash = (float*)u16;
    {
        float bj[2];
        bj[0] = bE[c0 + wc * 64 + 0  + (lane & 31)];
        bj[1] = bE[c0 + wc * 64 + 32 + (lane & 31)];
        #pragma unroll
        for (int i = 0; i < 2; ++i)
            #pragma unroll
            for (int j = 0; j < 2; ++j)
                #pragma unroll
                for (int rgi = 0; rgi < 16; ++rgi) {
                    int r = we * 64 + i * 32 + (rgi & 3) + 8 * (rgi >> 2) + 4 * (lane >> 5);
                    int c = wc * 64 + j * 32 + (lane & 31);
                    stash[r * 128 + c] = acc[i][j][rgi] + bj[j];
                }
    }
    __syncthreads();

    // ---- epilogue: 128 edges x 4 heads; each thread 2 (edge,head) pairs
    const int r = t >> 1;
    const int e = e0 + r;
    if (e < N_EDGES) {
        const int src = edge_index[e];
        const int dst = edge_index[N_EDGES + e];
        #pragma unroll
        for (int hh = 0; hh < 2; ++hh) {
            const int hl = (t & 1) + hh * 2;     // 0..3, head-local
            const int h  = ch * 4 + hl;          // global head

            const float4* K4 = (const float4*)(Kh + (size_t)src * OUTD + h * HD);
            const float4* Q4 = (const float4*)(Qh + (size_t)dst * OUTD + h * HD);
            float kq[16];
            #pragma unroll
            for (int i = 0; i < 4; ++i) {
                float4 kk = K4[i], qq = Q4[i];
                kq[i * 4 + 0] = kk.x + qq.x;
                kq[i * 4 + 1] = kk.y + qq.y;
                kq[i * 4 + 2] = kk.z + qq.z;
                kq[i * 4 + 3] = kk.w + qq.w;
            }

            float cv[16];
            float score = 0.f;
            #pragma unroll
            for (int d = 0; d < 16; ++d) {
                float s2 = stash[r * 128 + hl * 32 + d] * stash[r * 128 + hl * 32 + 16 + d];
                float sq = (s2 >= 0.f) ? sqrtf(s2) : -sqrtf(-s2);
                float c  = kq[d] + sq;
                cv[d] = c;
                score += c * Aw[d * NH + h];
            }
            float4* co = (float4*)(conn_out + (size_t)e * OUTD + h * HD);
            #pragma unroll
            for (int i = 0; i < 4; ++i)
                co[i] = make_float4(cv[i * 4 + 0], cv[i * 4 + 1],
                                    cv[i * 4 + 2], cv[i * 4 + 3]);

            score = fminf(fmaxf(score, -CLAMP_V), CLAMP_V);
            float ex = expf(score);
            exp_s[(size_t)e * NH + h] = ex;
            atomicAdd(&denom[(size_t)dst * NH + h], ex);
        }
    }
}

// ---------------------------------------------------------------------------
// Kernel 3: scatter pass (unchanged).
// ---------------------------------------------------------------------------
__global__ __launch_bounds__(256) void scatter_kernel(
    const int*   __restrict__ edge_index,
    const float* __restrict__ Vh,
    const float* __restrict__ conn,
    const float* __restrict__ exp_s,
    const float* __restrict__ denom,
    float* __restrict__ Vo,
    float* __restrict__ rowV)
{
    const int t = threadIdx.x;
    const int e = blockIdx.x * 2 + (t >> 7);
    const int c = t & 127;
    const int h = c >> 4;

    const int src = edge_index[e];
    const int dst = edge_index[N_EDGES + e];

    const float attn = exp_s[(size_t)e * NH + h] /
                       (denom[(size_t)dst * NH + h] + 1e-16f);

    const float mv = Vh[(size_t)src * OUTD + c] * attn;
    atomicAdd(&Vo[(size_t)dst * OUTD + c], mv);
    const float rv = conn[(size_t)e * OUTD + c] * attn;
    atomicAdd(&rowV[(size_t)dst * OUTD + c], rv);
}

// ---------------------------------------------------------------------------
// Kernel 4: finalize (unchanged).
// ---------------------------------------------------------------------------
__global__ __launch_bounds__(256) void finalize_kernel(
    const float* __restrict__ rowV,
    const float* __restrict__ VeRow,
    float* __restrict__ Vo)
{
    __shared__ float ver[2048];
    __shared__ float rv[256];
    const int t = threadIdx.x;

    #pragma unroll
    for (int it = 0; it < 2; ++it) {
        int idx = it * 256 + t;
        *(float4*)&ver[idx * 4] = *(const float4*)&VeRow[idx * 4];
    }
    const int n0 = blockIdx.x * 2;
    if (t < 64)
        *(float4*)&rv[t * 4] = *(const float4*)&rowV[(size_t)n0 * OUTD + t * 4];
    __syncthreads();

    const int nl = t >> 7, c = t & 127, h = c >> 4, cc = c & 15;
    float acc = 0.f;
    #pragma unroll
    for (int d = 0; d < 16; ++d)
        acc += rv[nl * 128 + h * 16 + d] * ver[d * 128 + h * 16 + cc];

    Vo[(size_t)(n0 + nl) * OUTD + c] += acc;
}

// ---------------------------------------------------------------------------
extern "C" void kernel_launch(void* const* d_in, const int* in_sizes, int n_in,
                              void* d_out, int out_size, void* d_ws, size_t ws_size,
                              hipStream_t stream)
{
    const float* x         = (const float*)d_in[0];
    const float* edge_attr = (const float*)d_in[1];
    const int*   edge_index= (const int*)  d_in[2];
    const float* WQ = (const float*)d_in[3];
    const float* bQ = (const float*)d_in[4];
    const float* WK = (const float*)d_in[5];
    const float* bK = (const float*)d_in[6];
    const float* WE = (const float*)d_in[7];
    const float* bE = (const float*)d_in[8];
    const float* WV = (const float*)d_in[9];
    const float* bV = (const float*)d_in[10];
    const float* Aw = (const float*)d_in[11];
    const float* VeRow = (const float*)d_in[12];

    float* Vo   = (float*)d_out;                       // [N,128]
    float* conn = Vo + (size_t)N_NODES * OUTD;         // [E,128]

    float* ws    = (float*)d_ws;
    float* Kh    = ws;                                 // N*128
    float* Vh    = Kh   + (size_t)N_NODES * OUTD;      // N*128
    float* rowV  = Vh   + (size_t)N_NODES * OUTD;      // N*128
    float* denom = rowV + (size_t)N_NODES * OUTD;      // N*8
    float* exp_s = denom+ (size_t)N_NODES * NH;        // E*8

    // Packed WE (bf16 hi/lo, transposed) lives in the TAIL of rowV:
    // it is consumed by edge_kernel, after which rowV is zeroed (below)
    // before scatter_kernel first touches it.  128 KB, no ws growth.
    ushort_t* WEt_hi = (ushort_t*)(rowV + (size_t)N_NODES * OUTD - 32768);
    ushort_t* WEt_lo = WEt_hi + 32768;

    hipMemsetAsync(denom, 0, (size_t)N_NODES * NH * sizeof(float), stream);

    pack_we_kernel<<<128, 256, 0, stream>>>(WE, WEt_hi, WEt_lo);

    dim3 g1((N_NODES + 63) / 64, 6);
    node_gemm_kernel<<<g1, 256, 0, stream>>>(x, WQ, bQ, WK, bK, WV, bV, Vo, Kh, Vh);

    const int nt = (N_EDGES + 127) / 128;              // 3907 edge tiles
    edge_kernel<<<nt * 2, 256, 0, stream>>>(edge_attr, edge_index, WEt_hi, WEt_lo,
                                            bE, Aw, Vo, Kh, conn, exp_s, denom);

    // rowV must be zero before scatter; also wipes the WEt scratch in its tail.
    hipMemsetAsync(rowV, 0, (size_t)N_NODES * OUTD * sizeof(float), stream);

    scatter_kernel<<<N_EDGES / 2, 256, 0, stream>>>(edge_index, Vh, conn,
                                                    exp_s, denom, Vo, rowV);

    finalize_kernel<<<N_NODES / 2, 256, 0, stream>>>(rowV, VeRow, Vo);
}